// Round 2
// baseline (2298.765 us; speedup 1.0000x reference)
//
#include <hip/hip_runtime.h>
#include <hip/hip_bf16.h>
#include <math.h>

// RSM: M=1000 columns, N=4 cells/col, K=25 winners, T=64, B=128, D_IN=1024, D_OUT=1024
#define MCOL   1000
#define NCELL  4
#define TCELL  4000
#define KWIN   25
#define TT     64
#define BB     128
#define DIN    1024
#define DOUT   1024

// ---------------------------------------------------------------------------
// Generic fp32 transpose: src[R][C] -> dst[C][R]
// ---------------------------------------------------------------------------
__global__ void transpose_k(const float* __restrict__ src, float* __restrict__ dst,
                            int R, int C) {
    __shared__ float tile[32][33];
    int c0 = blockIdx.x * 32, r0 = blockIdx.y * 32;
    int tx = threadIdx.x, ty = threadIdx.y;
#pragma unroll
    for (int q = 0; q < 4; ++q) {
        int r = r0 + ty + q * 8, c = c0 + tx;
        tile[ty + q * 8][tx] = (r < R && c < C) ? src[(size_t)r * C + c] : 0.f;
    }
    __syncthreads();
#pragma unroll
    for (int q = 0; q < 4; ++q) {
        int c = c0 + ty + q * 8, r = r0 + tx;
        if (c < C && r < R) dst[(size_t)c * R + r] = tile[tx][ty + q * 8];
    }
}

// ---------------------------------------------------------------------------
// ZA = X[8192,1024] @ w_a^T  -> [8192, 1000]   (fp32 vector GEMM, 128x128x16)
// ---------------------------------------------------------------------------
__launch_bounds__(256, 2)
__global__ void za_gemm(const float* __restrict__ A,   // [8192,1024]
                        const float* __restrict__ Bw,  // [1000,1024]
                        float* __restrict__ C) {       // [8192,1000]
    __shared__ float As[16][132];
    __shared__ float Bs[16][132];
    const int i0 = blockIdx.x * 128;
    const int m0 = blockIdx.y * 128;
    const int tid = threadIdx.x;
    const int tx = tid & 15, ty = tid >> 4;
    float acc[8][8];
#pragma unroll
    for (int a = 0; a < 8; ++a)
#pragma unroll
        for (int b = 0; b < 8; ++b) acc[a][b] = 0.f;

    for (int k0 = 0; k0 < DIN; k0 += 16) {
#pragma unroll
        for (int p = 0; p < 2; ++p) {
            int f = tid + p * 256;          // 0..511 float4 slots
            int row = f >> 2, c4 = (f & 3) * 4;
            float4 v = *reinterpret_cast<const float4*>(
                &A[(size_t)(i0 + row) * DIN + k0 + c4]);
            As[c4 + 0][row] = v.x; As[c4 + 1][row] = v.y;
            As[c4 + 2][row] = v.z; As[c4 + 3][row] = v.w;
            int m = m0 + row;
            float4 w = make_float4(0.f, 0.f, 0.f, 0.f);
            if (m < MCOL)
                w = *reinterpret_cast<const float4*>(&Bw[(size_t)m * DIN + k0 + c4]);
            Bs[c4 + 0][row] = w.x; Bs[c4 + 1][row] = w.y;
            Bs[c4 + 2][row] = w.z; Bs[c4 + 3][row] = w.w;
        }
        __syncthreads();
#pragma unroll
        for (int kk = 0; kk < 16; ++kk) {
            float4 a0 = *reinterpret_cast<const float4*>(&As[kk][ty * 8]);
            float4 a1 = *reinterpret_cast<const float4*>(&As[kk][ty * 8 + 4]);
            float4 b0 = *reinterpret_cast<const float4*>(&Bs[kk][tx * 8]);
            float4 b1 = *reinterpret_cast<const float4*>(&Bs[kk][tx * 8 + 4]);
            float av[8] = {a0.x, a0.y, a0.z, a0.w, a1.x, a1.y, a1.z, a1.w};
            float bv[8] = {b0.x, b0.y, b0.z, b0.w, b1.x, b1.y, b1.z, b1.w};
#pragma unroll
            for (int ii = 0; ii < 8; ++ii)
#pragma unroll
                for (int jj = 0; jj < 8; ++jj)
                    acc[ii][jj] = fmaf(av[ii], bv[jj], acc[ii][jj]);
        }
        __syncthreads();
    }
#pragma unroll
    for (int ii = 0; ii < 8; ++ii) {
        int i = i0 + ty * 8 + ii;
#pragma unroll
        for (int jj = 0; jj < 8; ++jj) {
            int m = m0 + tx * 8 + jj;
            if (m < MCOL) C[(size_t)i * MCOL + m] = acc[ii][jj];
        }
    }
}

// ---------------------------------------------------------------------------
// Persistent recurrence kernel: 1 WG (512 threads, 8 waves) per batch row.
// Thread t owns columns t and t+512 (latter if t<488). VGPR cap 256 -> deep MLP.
// ---------------------------------------------------------------------------
__launch_bounds__(512, 2)
__global__ void rsm_kernel(const float* __restrict__ ZA,   // [T*B, 1000]
                           const float* __restrict__ wbT,  // [4000,4000] = w_b^T
                           const float* __restrict__ wdT,  // [1000,1024] = w_d^T
                           const float* __restrict__ bd,   // [1024]
                           float* __restrict__ out) {      // [T*B, 1024]
    const int b = blockIdx.x;
    const int tid = threadIdx.x;
    const int lane = tid & 63, wid = tid >> 6;      // 8 waves
    const bool hasB = (tid < (MCOL - 512));         // 488 threads own a 2nd column
    const int c0 = tid, c1 = tid + 512;

    __shared__ int   hist0[8][256];
    __shared__ int   hist1[8][256];
    __shared__ int   sel[8];        // 0:b*0 1:above0 2:b*1 3:above1 4:candCnt 5:slotCnt
    __shared__ unsigned int candU[1024];
    __shared__ int   candI[1024];
    __shared__ int   wcellS[28];
    __shared__ float wdeltaS[28];
    __shared__ int   wcolS[28];
    __shared__ float wycolS[28];

    float Za[4] = {0,0,0,0}, Zb[4] = {0,0,0,0};
    float pha[4] = {0,0,0,0}, phb[4] = {0,0,0,0};
    float psa[4] = {0,0,0,0}, psb[4] = {0,0,0,0};
    const float breg0 = bd[tid], breg1 = bd[tid + 512];

    for (int t = 0; t < TT; ++t) {
        const float* zaRow = ZA + (size_t)(t * BB + b) * MCOL;
        float za0 = zaRow[c0];
        float za1 = hasB ? zaRow[c1] : 0.f;

        // ---- phase 1: sigma / pi / per-column max+argmax ----
        float sig0[4], sig1[4];
        float lam0 = -INFINITY, lam1 = -INFINITY;
        int an0 = 0, an1 = 0;
#pragma unroll
        for (int n = 0; n < 4; ++n) {
            sig0[n] = za0 + Za[n];
            float pi = sig0[n] * (1.0f - pha[n]);
            if (pi > lam0) { lam0 = pi; an0 = n; }
            sig1[n] = za1 + Zb[n];
            float pi1 = sig1[n] * (1.0f - phb[n]);
            if (pi1 > lam1) { lam1 = pi1; an1 = n; }
        }
        unsigned int ub0 = __float_as_uint(lam0);
        unsigned int u0 = (ub0 & 0x80000000u) ? ~ub0 : (ub0 | 0x80000000u);
        unsigned int ub1 = __float_as_uint(hasB ? lam1 : -INFINITY);
        unsigned int u1 = (ub1 & 0x80000000u) ? ~ub1 : (ub1 | 0x80000000u);

        // ---- init LDS (safe: all threads passed prev step's record barrier) ----
#pragma unroll
        for (int i = 0; i < 4; ++i) {
            ((int*)hist0)[tid + i * 512] = 0;
            ((int*)hist1)[tid + i * 512] = 0;
        }
        if (tid < 8) sel[tid] = 0;
        __syncthreads();                                             // B1

        float ysave0 = 0.f, ysave1 = 0.f;
        auto record0 = [&]() {
            int slot = atomicAdd(&sel[5], 1);
            float y = tanhf(sig0[an0]);
            float pdec = 0.5f * psa[an0];
            wcellS[slot]  = c0 * 4 + an0;
            wdeltaS[slot] = fmaxf(pdec, y) - pdec;
            wcolS[slot]   = c0;
            wycolS[slot]  = fmaxf(y, 0.f);
            ysave0 = y;
        };
        auto record1 = [&]() {
            int slot = atomicAdd(&sel[5], 1);
            float y = tanhf(sig1[an1]);
            float pdec = 0.5f * psb[an1];
            wcellS[slot]  = c1 * 4 + an1;
            wdeltaS[slot] = fmaxf(pdec, y) - pdec;
            wcolS[slot]   = c1;
            wycolS[slot]  = fmaxf(y, 0.f);
            ysave1 = y;
        };

        // ---- level 0: histogram on key byte 3 ----
        atomicAdd(&hist0[wid][u0 >> 24], 1);
        if (hasB) atomicAdd(&hist0[wid][u1 >> 24], 1);
        __syncthreads();                                             // B2
        if (wid == 0) {
            int h0 = 0, h1 = 0, h2 = 0, h3 = 0;
#pragma unroll
            for (int w = 0; w < 8; ++w) {
                h0 += hist0[w][lane * 4 + 0]; h1 += hist0[w][lane * 4 + 1];
                h2 += hist0[w][lane * 4 + 2]; h3 += hist0[w][lane * 4 + 3];
            }
            int s = h0 + h1 + h2 + h3;
            int p = s;
            for (int d = 1; d < 64; d <<= 1) {
                int q = __shfl_up(p, d);
                if (lane >= d) p += q;
            }
            int T_all = __shfl(p, 63);
            int pexc = p - s;
            int X = T_all - KWIN;
            int pr1 = pexc + h0, pr2 = pr1 + h1, pr3 = pr2 + h2;
            int lb = -1;
            if (pexc <= X) lb = lane * 4 + 0;
            if (pr1  <= X) lb = lane * 4 + 1;
            if (pr2  <= X) lb = lane * 4 + 2;
            if (pr3  <= X) lb = lane * 4 + 3;
            int bmax = lb;
            for (int d = 32; d; d >>= 1) bmax = max(bmax, __shfl_xor(bmax, d));
            if (lb == bmax && lb >= 0) {
                int k3 = bmax & 3;
                int prb = (k3 == 0) ? pexc : (k3 == 1) ? pr1 : (k3 == 2) ? pr2 : pr3;
                int hb  = (k3 == 0) ? h0   : (k3 == 1) ? h1  : (k3 == 2) ? h2  : h3;
                sel[0] = bmax;
                sel[1] = T_all - prb - hb;     // strictly above b*0
            }
        }
        __syncthreads();                                             // B3
        const int bstar0 = sel[0];
        const int byte00 = (int)(u0 >> 24), byte01 = (int)(u1 >> 24);
        const int act0 = (byte00 == bstar0);
        const int act1 = hasB && (byte01 == bstar0);
        // lev0-definite winners record now (overlaps with level 1)
        if (byte00 > bstar0) record0();
        if (hasB && byte01 > bstar0) record1();

        // ---- level 1: histogram on key byte 2 (boundary-bucket keys only) ----
        if (act0) atomicAdd(&hist1[wid][(u0 >> 16) & 255u], 1);
        if (act1) atomicAdd(&hist1[wid][(u1 >> 16) & 255u], 1);
        __syncthreads();                                             // B4
        if (wid == 0) {
            int need1 = KWIN - sel[1];
            int h0 = 0, h1 = 0, h2 = 0, h3 = 0;
#pragma unroll
            for (int w = 0; w < 8; ++w) {
                h0 += hist1[w][lane * 4 + 0]; h1 += hist1[w][lane * 4 + 1];
                h2 += hist1[w][lane * 4 + 2]; h3 += hist1[w][lane * 4 + 3];
            }
            int s = h0 + h1 + h2 + h3;
            int p = s;
            for (int d = 1; d < 64; d <<= 1) {
                int q = __shfl_up(p, d);
                if (lane >= d) p += q;
            }
            int T_all = __shfl(p, 63);
            int pexc = p - s;
            int X = T_all - need1;
            int pr1 = pexc + h0, pr2 = pr1 + h1, pr3 = pr2 + h2;
            int lb = -1;
            if (pexc <= X) lb = lane * 4 + 0;
            if (pr1  <= X) lb = lane * 4 + 1;
            if (pr2  <= X) lb = lane * 4 + 2;
            if (pr3  <= X) lb = lane * 4 + 3;
            int bmax = lb;
            for (int d = 32; d; d >>= 1) bmax = max(bmax, __shfl_xor(bmax, d));
            if (lb == bmax && lb >= 0) {
                int k3 = bmax & 3;
                int prb = (k3 == 0) ? pexc : (k3 == 1) ? pr1 : (k3 == 2) ? pr2 : pr3;
                int hb  = (k3 == 0) ? h0   : (k3 == 1) ? h1  : (k3 == 2) ? h2  : h3;
                sel[2] = bmax;
                sel[3] = T_all - prb - hb;
            }
        }
        __syncthreads();                                             // B5
        const int bstar1 = sel[2];
        const int need2 = (KWIN - sel[1]) - sel[3];
        const int byte10 = (int)((u0 >> 16) & 255u), byte11 = (int)((u1 >> 16) & 255u);
        const int a0b = act0 && (byte10 == bstar1);
        const int a1b = act1 && (byte11 == bstar1);
        if (act0 && byte10 > bstar1) record0();
        if (act1 && byte11 > bstar1) record1();
        if (a0b) { int s = atomicAdd(&sel[4], 1); candU[s] = u0; candI[s] = c0; }
        if (a1b) { int s = atomicAdd(&sel[4], 1); candU[s] = u1; candI[s] = c1; }
        __syncthreads();                                             // B6
        // ---- parallel tie cleanup: rank by (u desc, idx asc) ----
        const int c2 = sel[4];
        if (a0b) {
            int rank = 0;
            for (int j = 0; j < c2; ++j) {
                unsigned int cu = candU[j]; int ci = candI[j];
                rank += (cu > u0) || (cu == u0 && ci < c0);
            }
            if (rank < need2) record0();
        }
        if (a1b) {
            int rank = 0;
            for (int j = 0; j < c2; ++j) {
                unsigned int cu = candU[j]; int ci = candI[j];
                rank += (cu > u1) || (cu == u1 && ci < c1);
            }
            if (rank < need2) record1();
        }
        // ---- trace updates (registers; record() used pre-update psi) ----
#pragma unroll
        for (int n = 0; n < 4; ++n) {
            float yn0 = (n == an0) ? ysave0 : 0.f;
            psa[n] = fmaxf(0.5f * psa[n], yn0);
            pha[n] = fmaxf(0.5f * pha[n], yn0);
            Za[n] *= 0.5f;
            float yn1 = (n == an1) ? ysave1 : 0.f;
            psb[n] = fmaxf(0.5f * psb[n], yn1);
            phb[n] = fmaxf(0.5f * phb[n], yn1);
            Zb[n] *= 0.5f;
        }
        __syncthreads();                                             // B7

        // ---- gather: rank-25 Z update + sparse decode, max MLP ----
        float4 ga0[13], gb0[13];
#pragma unroll
        for (int j = 0; j < 13; ++j) {
            const float* p = wbT + (size_t)wcellS[j] * TCELL;
            ga0[j] = *reinterpret_cast<const float4*>(p + 4 * c0);
            gb0[j] = hasB ? *reinterpret_cast<const float4*>(p + 4 * c1)
                          : make_float4(0.f, 0.f, 0.f, 0.f);
        }
        float dv0[KWIN], dv1[KWIN];
#pragma unroll
        for (int j = 0; j < KWIN; ++j) {
            const float* q = wdT + (size_t)wcolS[j] * DOUT;
            dv0[j] = q[tid];
            dv1[j] = q[tid + 512];
        }
#pragma unroll
        for (int j = 0; j < 13; ++j) {
            float d = wdeltaS[j];
            Za[0] = fmaf(d, ga0[j].x, Za[0]); Za[1] = fmaf(d, ga0[j].y, Za[1]);
            Za[2] = fmaf(d, ga0[j].z, Za[2]); Za[3] = fmaf(d, ga0[j].w, Za[3]);
            Zb[0] = fmaf(d, gb0[j].x, Zb[0]); Zb[1] = fmaf(d, gb0[j].y, Zb[1]);
            Zb[2] = fmaf(d, gb0[j].z, Zb[2]); Zb[3] = fmaf(d, gb0[j].w, Zb[3]);
        }
        float4 ga1[12], gb1[12];
#pragma unroll
        for (int j = 0; j < 12; ++j) {
            const float* p = wbT + (size_t)wcellS[13 + j] * TCELL;
            ga1[j] = *reinterpret_cast<const float4*>(p + 4 * c0);
            gb1[j] = hasB ? *reinterpret_cast<const float4*>(p + 4 * c1)
                          : make_float4(0.f, 0.f, 0.f, 0.f);
        }
        float s0 = breg0, s1 = breg1;
#pragma unroll
        for (int j = 0; j < KWIN; ++j) {
            float yc = wycolS[j];
            s0 = fmaf(yc, dv0[j], s0);
            s1 = fmaf(yc, dv1[j], s1);
        }
#pragma unroll
        for (int j = 0; j < 12; ++j) {
            float d = wdeltaS[13 + j];
            Za[0] = fmaf(d, ga1[j].x, Za[0]); Za[1] = fmaf(d, ga1[j].y, Za[1]);
            Za[2] = fmaf(d, ga1[j].z, Za[2]); Za[3] = fmaf(d, ga1[j].w, Za[3]);
            Zb[0] = fmaf(d, gb1[j].x, Zb[0]); Zb[1] = fmaf(d, gb1[j].y, Zb[1]);
            Zb[2] = fmaf(d, gb1[j].z, Zb[2]); Zb[3] = fmaf(d, gb1[j].w, Zb[3]);
        }
        float* orow = out + (size_t)(t * BB + b) * DOUT;
        orow[tid] = s0;
        orow[tid + 512] = s1;
        // no trailing barrier: step t+1's first LDS writes come after B1.
    }
}

// ---------------------------------------------------------------------------
extern "C" void kernel_launch(void* const* d_in, const int* in_sizes, int n_in,
                              void* d_out, int out_size, void* d_ws, size_t ws_size,
                              hipStream_t stream) {
    const float* x   = (const float*)d_in[0];   // [64,128,1024]
    const float* w_a = (const float*)d_in[1];   // [1000,1024]
    const float* w_b = (const float*)d_in[2];   // [4000,4000]
    const float* w_d = (const float*)d_in[3];   // [1024,1000]
    const float* b_d = (const float*)d_in[4];   // [1024]
    float* out = (float*)d_out;                  // [64,128,1024]

    // workspace layout (floats): wbT[16e6] | wdT[1.024e6] | ZA[8.192e6]
    const size_t need_bytes = (size_t)(16000000 + 1024000 + 8192000) * 4;
    if (ws_size < need_bytes) return;  // insufficient scratch: fail loudly
    float* wbT = (float*)d_ws;
    float* wdT = wbT + 16000000;
    float* ZA  = wdT + 1024000;

    transpose_k<<<dim3(125, 125), dim3(32, 8), 0, stream>>>(w_b, wbT, TCELL, TCELL);
    transpose_k<<<dim3(32, 32),  dim3(32, 8), 0, stream>>>(w_d, wdT, DOUT, MCOL);
    za_gemm<<<dim3(64, 8), 256, 0, stream>>>(x, w_a, ZA);
    rsm_kernel<<<128, 512, 0, stream>>>(ZA, wbT, wdT, b_d, out);
}